// Round 5
// baseline (651.531 us; speedup 1.0000x reference)
//
#include <hip/hip_runtime.h>
#include <hip/hip_cooperative_groups.h>

namespace cg = cooperative_groups;

// BasicRNN R4: single persistent cooperative kernel (256 blocks x 512 thr).
// R3 budget analysis: ~85us of the 278 was inter-kernel launch gaps (14 dispatches
// at ~6us). Replace with 11 grid.sync()s. Step K-loop gets explicit register-rotated
// prefetch. Fragment-tiled operands as R2/R3:
//   elem(r,c) = frag*512 + lane*8 + (c&7), frag=(r>>5)*(C/16)+(c>>4), lane=(r&31)+32*((c>>3)&1)

typedef __bf16 bf16x8 __attribute__((ext_vector_type(8)));
typedef float  f32x16 __attribute__((ext_vector_type(16)));

#define TOTAL 4096
#define BATCH 256
#define INDIM 2048
#define SDIM  1024
#define NCLS  1000

#define MFMA(a, b, c) __builtin_amdgcn_mfma_f32_32x32x16_bf16((a), (b), (c), 0, 0, 0)

union ShMem {
    float trans[64][65];   // 16.6 KB (W transpose staging)
    float red8[8][1024];   // 32 KB   (E / out reduce)
    float buf4[4][4096];   // 64 KB   (step reduce)
};

__device__ inline f32x16 zero16() {
    f32x16 v;
#pragma unroll
    for (int i = 0; i < 16; ++i) v[i] = 0.f;
    return v;
}

__device__ inline void swz_dev(const float* __restrict__ in, __bf16* __restrict__ out,
                               int C, int Rvalid, int nslots, int gtid, int gstride) {
    for (int t = gtid; t < nslots; t += gstride) {
        const int lane = t & 63;
        const int frag = t >> 6;
        const int kcN = C >> 4;
        const int rt = frag / kcN;
        const int kc = frag - rt * kcN;
        const int r = rt * 32 + (lane & 31);
        const int c = kc * 16 + (lane >> 5) * 8;
        alignas(16) __bf16 v[8];
        if (r < Rvalid) {
            const float* p = in + (size_t)r * C + c;
#pragma unroll
            for (int j = 0; j < 8; ++j) v[j] = (__bf16)p[j];
        } else {
#pragma unroll
            for (int j = 0; j < 8; ++j) v[j] = (__bf16)0.f;
        }
        *(ulonglong2*)(out + (size_t)t * 8) = *(const ulonglong2*)v;
    }
}

// K-loop with 1-deep register-rotated prefetch: group i+1's 4KB issues before
// the MFMAs consuming group i, keeping ~4 groups in flight under unroll 4.
template <int PER>
__device__ inline void step_core(const bf16x8* __restrict__ A0, const bf16x8* __restrict__ A1,
                                 const bf16x8* __restrict__ B0, const bf16x8* __restrict__ B1,
                                 f32x16& ac0, f32x16& ac1, f32x16& ac2, f32x16& ac3) {
    bf16x8 a0 = A0[0], a1 = A1[0], b0 = B0[0], b1 = B1[0];
#pragma unroll 4
    for (int i = 0; i < PER - 1; ++i) {
        const int off = (i + 1) * 64;
        bf16x8 na0 = A0[off], na1 = A1[off], nb0 = B0[off], nb1 = B1[off];
        ac0 = MFMA(a0, b0, ac0);
        ac1 = MFMA(a0, b1, ac1);
        ac2 = MFMA(a1, b0, ac2);
        ac3 = MFMA(a1, b1, ac3);
        a0 = na0; a1 = na1; b0 = nb0; b1 = nb1;
    }
    ac0 = MFMA(a0, b0, ac0);
    ac1 = MFMA(a0, b1, ac1);
    ac2 = MFMA(a1, b0, ac2);
    ac3 = MFMA(a1, b1, ac3);
}

__global__ __launch_bounds__(512, 2) void k_mega(
    const float* __restrict__ x, const float* __restrict__ W,
    const float* __restrict__ in_w, const float* __restrict__ in_b,
    const float* __restrict__ out_w, const float* __restrict__ out_b,
    float* __restrict__ out, void* __restrict__ wsv) {
    __shared__ ShMem sh;
    cg::grid_group grid = cg::this_grid();

    char* ws = (char*)wsv;
    __bf16* WT   = (__bf16*)(ws + 0);          // 32 MiB  W^T tiled (r=n, c=k)
    __bf16* XT   = (__bf16*)(ws + 33554432);   // 1 MiB
    __bf16* IWT  = (__bf16*)(ws + 34603008);   // 4 MiB
    __bf16* OWT  = (__bf16*)(ws + 38797312);   // 2 MiB
    float*  Ebuf = (float*)(ws + 40894464);    // 1 MiB
    __bf16* H0   = (__bf16*)(ws + 41943040);   // 2 MiB
    __bf16* H1   = (__bf16*)(ws + 44040192);   // 2 MiB

    const int tid = threadIdx.x;
    const int bid = blockIdx.x;
    const int gtid = bid * 512 + tid;
    const int gstride = 256 * 512;
    const int wave = tid >> 6;
    const int lane = tid & 63;

    // ---------------- Phase A: swizzle x, in_w -> bf16 tiled ----------------
    swz_dev(x, XT, INDIM, BATCH, (BATCH / 32) * (INDIM / 16) * 64, gtid, gstride);
    swz_dev(in_w, IWT, INDIM, SDIM, (SDIM / 32) * (INDIM / 16) * 64, gtid, gstride);
    grid.sync();

    // ------- Phase B: E = x@in_w^T + b (one 32x32 tile/block), h0 = relu(E);
    //                  plus W transpose-swizzle (16 tiles/block) and out_w swizzle -------
    {
        const int mt = bid >> 5, nt = bid & 31;
        const int m0 = mt * 32, n0 = nt * 32;
        const int kc0 = wave * 16;
        const bf16x8* Ap = (const bf16x8*)XT + ((size_t)mt * (INDIM / 16) + kc0) * 64 + lane;
        const bf16x8* Bp = (const bf16x8*)IWT + ((size_t)nt * (INDIM / 16) + kc0) * 64 + lane;
        f32x16 acc = zero16();
#pragma unroll 4
        for (int i = 0; i < 16; ++i)
            acc = MFMA(Ap[i * 64], Bp[i * 64], acc);
#pragma unroll
        for (int r = 0; r < 16; ++r) {
            int row = (r & 3) + 8 * (r >> 2) + 4 * (lane >> 5);
            sh.red8[wave][row * 32 + (lane & 31)] = acc[r];
        }
        __syncthreads();
        const int e0 = tid * 2;
        float sx = 0.f, sy = 0.f;
#pragma unroll
        for (int w = 0; w < 8; ++w) {
            float2 v = *(const float2*)&sh.red8[w][e0];
            sx += v.x; sy += v.y;
        }
        const int row = e0 >> 5, col = e0 & 31;
        const int m = m0 + row, n = n0 + col;
        float v0 = sx + in_b[n], v1 = sy + in_b[n + 1];
        Ebuf[m * SDIM + n] = v0;
        Ebuf[m * SDIM + n + 1] = v1;
        __bf16 o[2];
        o[0] = (__bf16)fmaxf(v0, 0.f);
        o[1] = (__bf16)fmaxf(v1, 0.f);
        const size_t frag = (size_t)(m >> 5) * (TOTAL / 16) + (n >> 4);
        const int lh = (m & 31) + 32 * ((n >> 3) & 1);
        *(uint*)(H0 + frag * 512 + lh * 8 + (n & 7)) = *(const uint*)o;
        __syncthreads();   // LDS handoff red8 -> trans
    }
    {
        // W (f32, W[k][n]) -> WT tiled bf16 (r=n, c=k); 16 64x64 tiles per block
        const int x64 = tid & 63;
        const int y8 = tid >> 6;   // 0..7
        for (int it = 0; it < 16; ++it) {
            const int T = bid * 16 + it;
            const int n0 = (T & 63) * 64;
            const int k0 = (T >> 6) * 64;
#pragma unroll
            for (int r = y8; r < 64; r += 8)
                sh.trans[r][x64] = W[(size_t)(k0 + r) * TOTAL + n0 + x64];
            __syncthreads();
            const int frag = tid >> 6;    // 0..7
            const int lrt = frag >> 2, lkc = frag & 3;
            const int r_local = lrt * 32 + (x64 & 31);
            const int c_local = lkc * 16 + (x64 >> 5) * 8;
            alignas(16) __bf16 v[8];
#pragma unroll
            for (int j = 0; j < 8; ++j) v[j] = (__bf16)sh.trans[c_local + j][r_local];
            const size_t fragG = (size_t)((n0 >> 5) + lrt) * (TOTAL / 16) + (k0 >> 4) + lkc;
            *(ulonglong2*)(WT + fragG * 512 + x64 * 8) = *(const ulonglong2*)v;
            __syncthreads();   // protect trans before next tile overwrites
        }
        swz_dev(out_w, OWT, 1024, NCLS, (1024 / 32) * (1024 / 16) * 64, gtid, gstride);
    }
    grid.sync();

    // ---------------- Phase C: 9 recurrence steps ----------------
    const __bf16* hs = H0;
    __bf16* hd = H1;
    const int mtS = bid >> 6;   // 0..3  -> m0 = mtS*64
    const int ntS = bid & 63;   // 0..63 -> n0 = ntS*64
    for (int t = 1; t < 10; ++t) {
        const int chunks = (t == 1) ? (SDIM / 16) : (TOTAL / 16);
        const int per = chunks >> 3;
        const int kc0 = wave * per;
        const int gate = (t == 5);

        const bf16x8* A0 = (const bf16x8*)hs + ((size_t)(mtS * 2) * (TOTAL / 16) + kc0) * 64 + lane;
        const bf16x8* A1 = A0 + (size_t)(TOTAL / 16) * 64;
        const bf16x8* B0 = (const bf16x8*)WT + ((size_t)(ntS * 2) * (TOTAL / 16) + kc0) * 64 + lane;
        const bf16x8* B1 = B0 + (size_t)(TOTAL / 16) * 64;
        f32x16 ac0 = zero16(), ac1 = zero16(), ac2 = zero16(), ac3 = zero16();
        if (t == 1) step_core<8>(A0, A1, B0, B1, ac0, ac1, ac2, ac3);
        else        step_core<32>(A0, A1, B0, B1, ac0, ac1, ac2, ac3);

        // two-phase LDS reduce: idx(c,r,l) = (c*16+r)*64 + l (2-way bank alias: free)
        f32x16 accs[4] = {ac0, ac1, ac2, ac3};
        if (wave >= 4) {
            float* b = sh.buf4[wave - 4];
#pragma unroll
            for (int c = 0; c < 4; ++c)
#pragma unroll
                for (int r = 0; r < 16; ++r)
                    b[(c * 16 + r) * 64 + lane] = accs[c][r];
        }
        __syncthreads();
        if (wave < 4) {
            float* b = sh.buf4[wave];
#pragma unroll
            for (int c = 0; c < 4; ++c)
#pragma unroll
                for (int r = 0; r < 16; ++r) {
                    const int idx = (c * 16 + r) * 64 + lane;
                    b[idx] += accs[c][r];
                }
        }
        __syncthreads();

        // final 4-way sum + epilogue
        const int c = tid >> 7;          // 0..3
        const int r = (tid >> 3) & 15;   // 0..15
        const int l0 = (tid & 7) * 8;    // 0..56
        const int base = (c * 16 + r) * 64 + l0;
        float4 s0 = {0.f, 0.f, 0.f, 0.f}, s1 = {0.f, 0.f, 0.f, 0.f};
#pragma unroll
        for (int w = 0; w < 4; ++w) {
            const float4* p = (const float4*)&sh.buf4[w][base];
            float4 v0 = p[0], v1 = p[1];
            s0.x += v0.x; s0.y += v0.y; s0.z += v0.z; s0.w += v0.w;
            s1.x += v1.x; s1.y += v1.y; s1.z += v1.z; s1.w += v1.w;
        }
        float v[8] = {s0.x, s0.y, s0.z, s0.w, s1.x, s1.y, s1.z, s1.w};
        const int ih = c >> 1, jh = c & 1;
        const int row = ih * 32 + (r & 3) + 8 * (r >> 2) + 4 * (l0 >> 5);
        const int col0 = jh * 32 + (l0 & 31);
        const int m = mtS * 64 + row;
        const int n0g = ntS * 64 + col0;
        if (gate && n0g < SDIM) {
            const float* Ep = Ebuf + m * SDIM + n0g;
#pragma unroll
            for (int j = 0; j < 8; ++j) v[j] += Ep[j];
        }
        alignas(16) __bf16 o[8];
#pragma unroll
        for (int j = 0; j < 8; ++j) o[j] = (__bf16)fmaxf(v[j], 0.f);
        const size_t frag = (size_t)(m >> 5) * (TOTAL / 16) + (n0g >> 4);
        const int lh = (m & 31) + 32 * ((n0g >> 3) & 1);
        *(ulonglong2*)(hd + frag * 512 + lh * 8) = *(const ulonglong2*)o;

        grid.sync();
        const __bf16* tmp = hs; hs = hd; hd = (__bf16*)tmp;
    }

    // ---------------- Phase D: out = h[:,3072:] @ out_w^T + out_b ----------------
    {
        const int mt = bid >> 5, ct = bid & 31;
        const int m0 = mt * 32, c0 = ct * 32;
        const int kcA0 = (3072 / 16) + wave * 8;
        const int kcB0 = wave * 8;
        const bf16x8* Ap = (const bf16x8*)hs + ((size_t)mt * (TOTAL / 16) + kcA0) * 64 + lane;
        const bf16x8* Bp = (const bf16x8*)OWT + ((size_t)ct * (1024 / 16) + kcB0) * 64 + lane;
        f32x16 acc = zero16();
#pragma unroll
        for (int i = 0; i < 8; ++i)
            acc = MFMA(Ap[i * 64], Bp[i * 64], acc);
#pragma unroll
        for (int r = 0; r < 16; ++r) {
            int row = (r & 3) + 8 * (r >> 2) + 4 * (lane >> 5);
            sh.red8[wave][row * 32 + (lane & 31)] = acc[r];
        }
        __syncthreads();
        const int e0 = tid * 2;
        float sx = 0.f, sy = 0.f;
#pragma unroll
        for (int w = 0; w < 8; ++w) {
            float2 v = *(const float2*)&sh.red8[w][e0];
            sx += v.x; sy += v.y;
        }
        const int row = e0 >> 5, col = e0 & 31;
        const int m = m0 + row;
        const int n = c0 + col;
        if (n < NCLS)     out[m * NCLS + n] = sx + out_b[n];
        if (n + 1 < NCLS) out[m * NCLS + n + 1] = sy + out_b[n + 1];
    }
}

extern "C" void kernel_launch(void* const* d_in, const int* in_sizes, int n_in,
                              void* d_out, int out_size, void* d_ws, size_t ws_size,
                              hipStream_t stream) {
    const float* x     = (const float*)d_in[0];   // 256 x 2048
    const float* W     = (const float*)d_in[1];   // 4096 x 4096
    const float* in_w  = (const float*)d_in[2];   // 1024 x 2048
    const float* in_b  = (const float*)d_in[3];   // 1024
    const float* out_w = (const float*)d_in[4];   // 1000 x 1024
    const float* out_b = (const float*)d_in[5];   // 1000
    float* out = (float*)d_out;                   // 256 x 1000
    void* wsv = d_ws;

    void* args[] = {(void*)&x, (void*)&W, (void*)&in_w, (void*)&in_b,
                    (void*)&out_w, (void*)&out_b, (void*)&out, (void*)&wsv};
    hipLaunchCooperativeKernel((const void*)k_mega, dim3(256), dim3(512), args, 0, stream);
}

// Round 6
// 291.615 us; speedup vs baseline: 2.2342x; 2.2342x over previous
//
#include <hip/hip_runtime.h>

// BasicRNN R5: revert R4's cooperative kernel (grid.sync ~30us each on 8-XCD = +330us).
// Multi-kernel R3 structure + (a) 4 preproc kernels merged into one block-partitioned
// k_prep, (b) k_step K-loop gets explicit depth-4 rotated register prefetch (16KB/wave
// in flight) to cover L2/L3 latency at 8 waves/CU. Fragment-tiled operands:
//   elem(r,c) = frag*512 + lane*8 + (c&7), frag=(r>>5)*(C/16)+(c>>4), lane=(r&31)+32*((c>>3)&1)

typedef __bf16 bf16x8 __attribute__((ext_vector_type(8)));
typedef float  f32x16 __attribute__((ext_vector_type(16)));

#define TOTAL 4096
#define BATCH 256
#define INDIM 2048
#define SDIM  1024
#define NCLS  1000

#define MFMA(a, b, c) __builtin_amdgcn_mfma_f32_32x32x16_bf16((a), (b), (c), 0, 0, 0)

__device__ inline f32x16 zero16() {
    f32x16 v;
#pragma unroll
    for (int i = 0; i < 16; ++i) v[i] = 0.f;
    return v;
}

__device__ inline void swz_slot(const float* __restrict__ in, __bf16* __restrict__ out,
                                int C, int Rvalid, int t) {
    const int lane = t & 63;
    const int frag = t >> 6;
    const int kcN = C >> 4;
    const int rt = frag / kcN;
    const int kc = frag - rt * kcN;
    const int r = rt * 32 + (lane & 31);
    const int c = kc * 16 + (lane >> 5) * 8;
    alignas(16) __bf16 v[8];
    if (r < Rvalid) {
        const float* p = in + (size_t)r * C + c;
#pragma unroll
        for (int j = 0; j < 8; ++j) v[j] = (__bf16)p[j];
    } else {
#pragma unroll
        for (int j = 0; j < 8; ++j) v[j] = (__bf16)0.f;
    }
    *(ulonglong2*)(out + (size_t)t * 8) = *(const ulonglong2*)v;
}

// ---- merged preprocessing: W transpose-swizzle + x/in_w/out_w swizzle-cvt ----
// grid 5888 x 256: [0,4096) W tiles; [4096,4352) x; [4352,5376) in_w; [5376,5888) out_w
__global__ __launch_bounds__(256) void k_prep(const float* __restrict__ W,
                                              const float* __restrict__ x,
                                              const float* __restrict__ in_w,
                                              const float* __restrict__ out_w,
                                              __bf16* __restrict__ WT,
                                              __bf16* __restrict__ XT,
                                              __bf16* __restrict__ IWT,
                                              __bf16* __restrict__ OWT) {
    const int bid = blockIdx.x;
    const int tid = threadIdx.x;
    if (bid < 4096) {
        __shared__ float t[64][65];
        const int n0 = (bid & 63) * 64;
        const int k0 = (bid >> 6) * 64;
        const int x64 = tid & 63;
        const int y = tid >> 6;
#pragma unroll
        for (int r = y; r < 64; r += 4)
            t[r][x64] = W[(size_t)(k0 + r) * TOTAL + (n0 + x64)];
        __syncthreads();
#pragma unroll
        for (int s = tid; s < 512; s += 256) {
            const int frag = s >> 6;
            const int lane = s & 63;
            const int lrt = frag >> 2;
            const int lkc = frag & 3;
            const int r_local = lrt * 32 + (lane & 31);
            const int c_local = lkc * 16 + (lane >> 5) * 8;
            alignas(16) __bf16 v[8];
#pragma unroll
            for (int j = 0; j < 8; ++j) v[j] = (__bf16)t[c_local + j][r_local];
            const size_t fragG = (size_t)((n0 >> 5) + lrt) * (TOTAL / 16) + ((k0 >> 4) + lkc);
            *(ulonglong2*)(WT + fragG * 512 + lane * 8) = *(const ulonglong2*)v;
        }
    } else if (bid < 4352) {
        swz_slot(x, XT, INDIM, BATCH, (bid - 4096) * 256 + tid);
    } else if (bid < 5376) {
        swz_slot(in_w, IWT, INDIM, SDIM, (bid - 4352) * 256 + tid);
    } else {
        swz_slot(out_w, OWT, 1024, NCLS, (bid - 5376) * 256 + tid);
    }
}

// ---- E = x @ in_w^T + in_b ; h0[:, :1024] = relu(E) (tiled) ----
__global__ __launch_bounds__(512, 4) void k_gemm_E(const __bf16* __restrict__ xt,
                                                   const __bf16* __restrict__ iwt,
                                                   const float* __restrict__ in_b,
                                                   float* __restrict__ E,
                                                   __bf16* __restrict__ h0) {
    __shared__ float red[8][1024];
    const int wave = threadIdx.x >> 6;
    const int lane = threadIdx.x & 63;
    const int mt = blockIdx.x >> 5;
    const int nt = blockIdx.x & 31;
    const int m0 = mt * 32, n0 = nt * 32;
    const int kc0 = wave * 16;
    const bf16x8* Ap = (const bf16x8*)xt  + ((size_t)mt * (INDIM / 16) + kc0) * 64 + lane;
    const bf16x8* Bp = (const bf16x8*)iwt + ((size_t)nt * (INDIM / 16) + kc0) * 64 + lane;
    f32x16 acc = zero16();
#pragma unroll 4
    for (int i = 0; i < 16; ++i)
        acc = MFMA(Ap[i * 64], Bp[i * 64], acc);
#pragma unroll
    for (int r = 0; r < 16; ++r) {
        int row = (r & 3) + 8 * (r >> 2) + 4 * (lane >> 5);
        red[wave][row * 32 + (lane & 31)] = acc[r];
    }
    __syncthreads();
    const int e0 = threadIdx.x * 2;
    float sx = 0.f, sy = 0.f;
#pragma unroll
    for (int w = 0; w < 8; ++w) {
        float2 v = *(const float2*)&red[w][e0];
        sx += v.x; sy += v.y;
    }
    const int row = e0 >> 5, col = e0 & 31;
    const int m = m0 + row, n = n0 + col;
    float v0 = sx + in_b[n], v1 = sy + in_b[n + 1];
    E[m * SDIM + n]     = v0;
    E[m * SDIM + n + 1] = v1;
    __bf16 o[2];
    o[0] = (__bf16)fmaxf(v0, 0.f);
    o[1] = (__bf16)fmaxf(v1, 0.f);
    const size_t frag = (size_t)(m >> 5) * (TOTAL / 16) + (n >> 4);
    const int lh = (m & 31) + 32 * ((n >> 3) & 1);
    *(uint*)(h0 + frag * 512 + lh * 8 + (n & 7)) = *(const uint*)o;
}

// depth-4 rotated register prefetch K-loop: 16 loads (16KB/wave) in flight
template <int PER>
__device__ inline void step_core(const bf16x8* __restrict__ A0p, const bf16x8* __restrict__ A1p,
                                 const bf16x8* __restrict__ B0p, const bf16x8* __restrict__ B1p,
                                 f32x16& ac0, f32x16& ac1, f32x16& ac2, f32x16& ac3) {
    constexpr int D = 4;
    bf16x8 a0[D], a1[D], b0[D], b1[D];
#pragma unroll
    for (int d = 0; d < D; ++d) {
        const int off = d * 64;
        a0[d] = A0p[off]; a1[d] = A1p[off];
        b0[d] = B0p[off]; b1[d] = B1p[off];
    }
#pragma unroll
    for (int i = 0; i < PER; ++i) {
        const int s = i & (D - 1);
        bf16x8 ca0 = a0[s], ca1 = a1[s], cb0 = b0[s], cb1 = b1[s];
        if (i + D < PER) {
            const int off = (i + D) * 64;
            a0[s] = A0p[off]; a1[s] = A1p[off];
            b0[s] = B0p[off]; b1[s] = B1p[off];
        }
        ac0 = MFMA(ca0, cb0, ac0);
        ac1 = MFMA(ca0, cb1, ac1);
        ac2 = MFMA(ca1, cb0, ac2);
        ac3 = MFMA(ca1, cb1, ac3);
    }
}

// ---- one recurrence step: hn = relu(h @ W + gate*[E,0,0]) (h, hn, WT tiled) ----
// 256 blocks x 512 thr; block/wave tile 64m x 64n; 8 waves K-split
template <int CHUNKS>
__global__ __launch_bounds__(512, 2) void k_step(const __bf16* __restrict__ h,
                                                 const __bf16* __restrict__ WT,
                                                 const float* __restrict__ E,
                                                 const int gate,
                                                 __bf16* __restrict__ hn) {
    __shared__ float buf[4][4096];   // 64 KiB
    const int wave = threadIdx.x >> 6;
    const int lane = threadIdx.x & 63;
    const int mt = blockIdx.x >> 6;    // 0..3  -> m0 = mt*64
    const int nt = blockIdx.x & 63;    // 0..63 -> n0 = nt*64
    constexpr int PER = CHUNKS >> 3;
    const int kc0 = wave * PER;

    const bf16x8* A0 = (const bf16x8*)h  + ((size_t)(mt * 2) * (TOTAL / 16) + kc0) * 64 + lane;
    const bf16x8* A1 = A0 + (size_t)(TOTAL / 16) * 64;
    const bf16x8* B0 = (const bf16x8*)WT + ((size_t)(nt * 2) * (TOTAL / 16) + kc0) * 64 + lane;
    const bf16x8* B1 = B0 + (size_t)(TOTAL / 16) * 64;

    f32x16 ac0 = zero16(), ac1 = zero16(), ac2 = zero16(), ac3 = zero16();
    step_core<PER>(A0, A1, B0, B1, ac0, ac1, ac2, ac3);

    // two-phase reduce: idx(c,r,l) = (c*16+r)*64 + l (2-way bank alias: free)
    f32x16 accs[4] = {ac0, ac1, ac2, ac3};
    if (wave >= 4) {
        float* b = buf[wave - 4];
#pragma unroll
        for (int c = 0; c < 4; ++c)
#pragma unroll
            for (int r = 0; r < 16; ++r)
                b[(c * 16 + r) * 64 + lane] = accs[c][r];
    }
    __syncthreads();
    if (wave < 4) {
        float* b = buf[wave];
#pragma unroll
        for (int c = 0; c < 4; ++c)
#pragma unroll
            for (int r = 0; r < 16; ++r) {
                const int idx = (c * 16 + r) * 64 + lane;
                b[idx] += accs[c][r];
            }
    }
    __syncthreads();

    // final 4-way sum + epilogue; thread t -> (c, r, 8 lanes from l0)
    const int t = threadIdx.x;
    const int c = t >> 7;            // 0..3
    const int r = (t >> 3) & 15;     // 0..15
    const int l0 = (t & 7) * 8;      // 0..56
    const int base = (c * 16 + r) * 64 + l0;
    float4 s0 = {0.f, 0.f, 0.f, 0.f}, s1 = {0.f, 0.f, 0.f, 0.f};
#pragma unroll
    for (int w = 0; w < 4; ++w) {
        const float4* p = (const float4*)&buf[w][base];
        float4 v0 = p[0], v1 = p[1];
        s0.x += v0.x; s0.y += v0.y; s0.z += v0.z; s0.w += v0.w;
        s1.x += v1.x; s1.y += v1.y; s1.z += v1.z; s1.w += v1.w;
    }
    float v[8] = {s0.x, s0.y, s0.z, s0.w, s1.x, s1.y, s1.z, s1.w};
    const int ih = c >> 1, jh = c & 1;
    const int row = ih * 32 + (r & 3) + 8 * (r >> 2) + 4 * (l0 >> 5);
    const int col0 = jh * 32 + (l0 & 31);
    const int m = mt * 64 + row;
    const int n0g = nt * 64 + col0;
    if (gate && n0g < SDIM) {
        const float* Ep = E + m * SDIM + n0g;
#pragma unroll
        for (int j = 0; j < 8; ++j) v[j] += Ep[j];
    }
    alignas(16) __bf16 o[8];
#pragma unroll
    for (int j = 0; j < 8; ++j) o[j] = (__bf16)fmaxf(v[j], 0.f);
    const size_t frag = (size_t)(m >> 5) * (TOTAL / 16) + (n0g >> 4);
    const int lh = (m & 31) + 32 * ((n0g >> 3) & 1);
    *(ulonglong2*)(hn + frag * 512 + lh * 8) = *(const ulonglong2*)o;
}

// ---- out = h[:, 3072:] @ out_w^T + out_b (h tiled, out_w tiled padded to 1024 rows) ----
__global__ __launch_bounds__(512, 4) void k_out(const __bf16* __restrict__ h,
                                                const __bf16* __restrict__ owt,
                                                const float* __restrict__ out_b,
                                                float* __restrict__ out) {
    __shared__ float red[8][1024];
    const int wave = threadIdx.x >> 6;
    const int lane = threadIdx.x & 63;
    const int mt = blockIdx.x >> 5;
    const int ct = blockIdx.x & 31;
    const int m0 = mt * 32, c0 = ct * 32;
    const int kcA0 = (3072 / 16) + wave * 8;
    const int kcB0 = wave * 8;
    const bf16x8* Ap = (const bf16x8*)h   + ((size_t)mt * (TOTAL / 16) + kcA0) * 64 + lane;
    const bf16x8* Bp = (const bf16x8*)owt + ((size_t)ct * (1024 / 16) + kcB0) * 64 + lane;
    f32x16 acc = zero16();
#pragma unroll
    for (int i = 0; i < 8; ++i)
        acc = MFMA(Ap[i * 64], Bp[i * 64], acc);
#pragma unroll
    for (int r = 0; r < 16; ++r) {
        int row = (r & 3) + 8 * (r >> 2) + 4 * (lane >> 5);
        red[wave][row * 32 + (lane & 31)] = acc[r];
    }
    __syncthreads();
    const int e0 = threadIdx.x * 2;
    float sx = 0.f, sy = 0.f;
#pragma unroll
    for (int w = 0; w < 8; ++w) {
        float2 v = *(const float2*)&red[w][e0];
        sx += v.x; sy += v.y;
    }
    const int row = e0 >> 5, col = e0 & 31;
    const int m = m0 + row;
    const int n = c0 + col;
    if (n < NCLS)     out[m * NCLS + n]     = sx + out_b[n];
    if (n + 1 < NCLS) out[m * NCLS + n + 1] = sy + out_b[n + 1];
}

extern "C" void kernel_launch(void* const* d_in, const int* in_sizes, int n_in,
                              void* d_out, int out_size, void* d_ws, size_t ws_size,
                              hipStream_t stream) {
    const float* x     = (const float*)d_in[0];   // 256 x 2048
    const float* W     = (const float*)d_in[1];   // 4096 x 4096
    const float* in_w  = (const float*)d_in[2];   // 1024 x 2048
    const float* in_b  = (const float*)d_in[3];   // 1024
    const float* out_w = (const float*)d_in[4];   // 1000 x 1024
    const float* out_b = (const float*)d_in[5];   // 1000
    float* out = (float*)d_out;                   // 256 x 1000

    char* ws = (char*)d_ws;
    __bf16* WT  = (__bf16*)(ws + 0);          // 32 MiB  W^T tiled (r=n, c=k)
    __bf16* XT  = (__bf16*)(ws + 33554432);   // 1 MiB   x tiled
    __bf16* IWT = (__bf16*)(ws + 34603008);   // 4 MiB   in_w tiled
    __bf16* OWT = (__bf16*)(ws + 38797312);   // 2 MiB   out_w tiled (padded 1024 rows)
    float*  Ebuf= (float*)(ws + 40894464);    // 1 MiB   E f32 row-major
    __bf16* H0  = (__bf16*)(ws + 41943040);   // 2 MiB   h tiled
    __bf16* H1  = (__bf16*)(ws + 44040192);   // 2 MiB   h tiled

    k_prep<<<5888, 256, 0, stream>>>(W, x, in_w, out_w, WT, XT, IWT, OWT);

    // t = 0: h = [relu(E), 0, 0] (gate=1, h was zero). No memset needed:
    // k_gemm_E writes cols [0,1024); step t=1 reads only K<1024.
    k_gemm_E<<<256, 512, 0, stream>>>(XT, IWT, in_b, Ebuf, H0);

    // t = 1..9 (gate fires at t=5); t=1 only needs K=1024 (h1 cols >=1024 are zero)
    const __bf16* hs = H0;
    __bf16* hd = H1;
    for (int t = 1; t < 10; ++t) {
        const int gate = (t % 5 == 0) ? 1 : 0;
        if (t == 1)
            k_step<SDIM / 16><<<256, 512, 0, stream>>>(hs, WT, Ebuf, gate, hd);
        else
            k_step<TOTAL / 16><<<256, 512, 0, stream>>>(hs, WT, Ebuf, gate, hd);
        const __bf16* tmp = hs; hs = hd; hd = (__bf16*)tmp;
    }

    k_out<<<256, 512, 0, stream>>>(hs, OWT, out_b, out);
}